// Round 6
// baseline (20121.291 us; speedup 1.0000x reference)
//
#include <hip/hip_runtime.h>
#include <cstdint>
#include <math.h>

#define U 896
#define HU 448
#define TU 2688
#define BB 8
#define TT 512
#define MM 80
#define CC 256
#define NTH 512
#define NBLK 72

// ---------------- Threefry-2x32 (JAX partitionable) ----------------
__device__ __forceinline__ uint32_t rotl32(uint32_t v, int r){ return (v<<r)|(v>>(32-r)); }

__device__ void threefry(uint32_t k0, uint32_t k1, uint32_t x0, uint32_t x1,
                         uint32_t* o0, uint32_t* o1){
  uint32_t k2 = k0 ^ k1 ^ 0x1BD11BDAu;
  x0 += k0; x1 += k1;
  x0+=x1; x1=rotl32(x1,13); x1^=x0;
  x0+=x1; x1=rotl32(x1,15); x1^=x0;
  x0+=x1; x1=rotl32(x1,26); x1^=x0;
  x0+=x1; x1=rotl32(x1, 6); x1^=x0;
  x0+=k1; x1+=k2+1u;
  x0+=x1; x1=rotl32(x1,17); x1^=x0;
  x0+=x1; x1=rotl32(x1,29); x1^=x0;
  x0+=x1; x1=rotl32(x1,16); x1^=x0;
  x0+=x1; x1=rotl32(x1,24); x1^=x0;
  x0+=k2; x1+=k0+2u;
  x0+=x1; x1=rotl32(x1,13); x1^=x0;
  x0+=x1; x1=rotl32(x1,15); x1^=x0;
  x0+=x1; x1=rotl32(x1,26); x1^=x0;
  x0+=x1; x1=rotl32(x1, 6); x1^=x0;
  x0+=k0; x1+=k1+3u;
  x0+=x1; x1=rotl32(x1,17); x1^=x0;
  x0+=x1; x1=rotl32(x1,29); x1^=x0;
  x0+=x1; x1=rotl32(x1,16); x1^=x0;
  x0+=x1; x1=rotl32(x1,24); x1^=x0;
  x0+=k1; x1+=k2+4u;
  x0+=x1; x1=rotl32(x1,13); x1^=x0;
  x0+=x1; x1=rotl32(x1,15); x1^=x0;
  x0+=x1; x1=rotl32(x1,26); x1^=x0;
  x0+=x1; x1=rotl32(x1, 6); x1^=x0;
  x0+=k2; x1+=k0+5u;
  *o0 = x0; *o1 = x1;
}

__device__ float gumbel_from(uint32_t ka, uint32_t kb, uint32_t e){
  uint32_t o0, o1;
  threefry(ka, kb, 0u, e, &o0, &o1);
  uint32_t bits = o0 ^ o1;
  uint32_t m = bits >> 9;
  float u = (m == 0u) ? 1.17549435e-38f
                      : (__uint_as_float(m | 0x3f800000u) - 1.0f);
  float l1 = (float)log((double)u);
  float l2 = (float)log((double)(-l1));
  return -l2;
}

__device__ __forceinline__ float sig_f(float x){
  return (float)(0.5 + 0.5*tanh(0.5*(double)x));
}
__device__ __forceinline__ float tanh_f(float x){ return (float)tanh((double)x); }

// ---------------- coherent (agent-scope) access ----------------
__device__ __forceinline__ float gldf(const float* p){
  return __hip_atomic_load(p, __ATOMIC_RELAXED, __HIP_MEMORY_SCOPE_AGENT);
}
__device__ __forceinline__ void gstf(float* p, float v){
  __hip_atomic_store(p, v, __ATOMIC_RELAXED, __HIP_MEMORY_SCOPE_AGENT);
}
__device__ __forceinline__ int gldi(const int* p){
  return __hip_atomic_load(p, __ATOMIC_RELAXED, __HIP_MEMORY_SCOPE_AGENT);
}
__device__ __forceinline__ void gsti(int* p, int v){
  __hip_atomic_store(p, v, __ATOMIC_RELAXED, __HIP_MEMORY_SCOPE_AGENT);
}

// per-producer slots, 128B apart (32 u32); busy-spin (no s_sleep)
__device__ __forceinline__ void wait_slots(const uint32_t* slots, int n, uint32_t tgt, int tid){
  if (tid < n){
    const uint32_t* p = slots + (size_t)tid*32;
    int it = 0;
    while (__hip_atomic_load(p, __ATOMIC_RELAXED, __HIP_MEMORY_SCOPE_AGENT) < tgt){
      if (++it > (1<<24)) break;
    }
  }
  __syncthreads();
}
__device__ __forceinline__ void publish_slot(uint32_t* slot, uint32_t v, int tid){
  __syncthreads();
  if (tid == 0)
    __hip_atomic_store(slot, v, __ATOMIC_RELEASE, __HIP_MEMORY_SCOPE_AGENT);
}

__device__ __forceinline__ void fma4(float4& a, const float4& w, float h){
  a.x += w.x*h; a.y += w.y*h; a.z += w.z*h; a.w += w.w*h;
}

// butterfly-sum 8 float4 accumulators over lane bits 3..5
__device__ __forceinline__ void bf8(float4* a){
  #pragma unroll
  for (int d=8; d<64; d<<=1){
    #pragma unroll
    for (int b=0;b<8;++b){
      a[b].x += __shfl_xor(a[b].x, d);
      a[b].y += __shfl_xor(a[b].y, d);
      a[b].z += __shfl_xor(a[b].z, d);
      a[b].w += __shfl_xor(a[b].w, d);
    }
  }
}

// ---------------- K0: per-step keys ----------------
__global__ __launch_bounds__(256) void k_keys(uint32_t* __restrict__ kc, uint32_t* __restrict__ kf){
  int t = blockIdx.x*256 + threadIdx.x;
  if (t >= TT) return;
  uint32_t ka, kb;
  threefry(0u, 42u, 0u, (uint32_t)t, &ka, &kb);
  uint32_t c0,c1,f0,f1;
  threefry(ka, kb, 0u, 0u, &c0, &c1);
  threefry(ka, kb, 0u, 1u, &f0, &f1);
  kc[2*t] = c0; kc[2*t+1] = c1;
  kf[2*t] = f0; kf[2*t+1] = f1;
}

// ws offsets
#define O_SH1   0
#define O_SH1HI 1024
#define O_SFV   2048
#define O_SG    3072
#define O_SYC   6656
#define O_SYF   10240
#define O_KC    13824
#define O_KF    17920
#define O_NCV   22016
#define O_FVS   22080
#define O_NCI   22144
#define O_PRE   22272
#define O_IHB   108288
#define O_HGL   136960
#define O_H0C   194304
#define O_PLC   208640
#define O_PLF   438016
#define WS_ZERO 667392

// ---------------- persistent kernel ----------------
__global__ __launch_bounds__(NTH, 2) void wavernn_persist(
    const float* __restrict__ mels, const float* __restrict__ Wk,
    const float* __restrict__ Wr,  const float* __restrict__ bias,
    const float* __restrict__ W1c, const float* __restrict__ b1c,
    const float* __restrict__ W2c, const float* __restrict__ b2c,
    const float* __restrict__ W1f, const float* __restrict__ b1f,
    const float* __restrict__ W2f, const float* __restrict__ b2f,
    float* __restrict__ out, char* __restrict__ ws)
{
  uint32_t* SH1   = (uint32_t*)(ws + O_SH1);
  uint32_t* SH1HI = (uint32_t*)(ws + O_SH1HI);
  uint32_t* SFV   = (uint32_t*)(ws + O_SFV);
  uint32_t* SG    = (uint32_t*)(ws + O_SG);
  uint32_t* SYC   = (uint32_t*)(ws + O_SYC);
  uint32_t* SYF   = (uint32_t*)(ws + O_SYF);
  const uint32_t* kc = (const uint32_t*)(ws + O_KC);
  const uint32_t* kf = (const uint32_t*)(ws + O_KF);
  float* ncvB = (float*)(ws + O_NCV);   // [2][8]
  float* fvsB = (float*)(ws + O_FVS);   // [2][8]
  int*   nci  = (int*)  (ws + O_NCI);
  float* pre  = (float*)(ws + O_PRE);   // [8][2688]
  float* ihb  = (float*)(ws + O_IHB);   // [8][896]
  float* hgl  = (float*)(ws + O_HGL);   // [2][8*896]
  float* h0c  = (float*)(ws + O_H0C);   // [8][448]
  float* plgtC= (float*)(ws + O_PLC);   // [28][8][256]
  float* plgtF= (float*)(ws + O_PLF);   // [28][8][256]

  __shared__ __align__(16) char smem[46080];
  const int bk = blockIdx.x, tid = threadIdx.x;

  if (bk < 28){
    // ================= GEMM + coarse-gates epilogue =================
    const int c4i = tid & 7, ks = tid >> 3;
    const int k0 = ks*14;
    const int lane = tid & 63, wv = tid >> 6;
    const int U0 = bk*32;
    const int cb0 = U0 + c4i*4;
    float* hlf   = (float*)smem;                 // [8][1024] = 32KB
    float* wredf = (float*)(smem + 32768);       // 9216B
    float* gbuf  = (float*)(smem + 41984);       // 4KB
    const int xk = 896 + ks*2;
    const int r0 = ((xk   < 978) ? xk   : 978) - 896;
    const int r1 = ((xk+1 < 978) ? xk+1 : 978) - 896;

    for (int t=0; t<TT; ++t){
      wait_slots(SH1, 8, (uint32_t)t, tid);
      const int hs = (t&1)*7168;
      for (int i=tid;i<8192;i+=NTH){
        const int b = i>>10, k = i&1023;
        float v;
        if (k < 896)      v = gldf(hgl + hs + b*896 + k);
        else if (k < 976) v = mels[((size_t)b*TT + t)*MM + (k-896)];
        else if (k == 976)v = gldf(ncvB + ((t+1)&1)*8 + b);
        else              v = 0.f;
        hlf[i] = v;
      }
      __syncthreads();

      for (int g=0; g<3; ++g){
        const int cbg = g*896 + cb0;
        float4 aW[8], aX[8];
        #pragma unroll
        for (int b=0;b<8;++b){ aW[b]=make_float4(0,0,0,0); aX[b]=make_float4(0,0,0,0); }
        #pragma unroll 2
        for (int j=0;j<14;++j){
          const float4 w = *(const float4*)(Wr + (size_t)(k0+j)*TU + cbg);
          #pragma unroll
          for (int b=0;b<8;++b) fma4(aW[b], w, hlf[b*1024 + k0 + j]);
        }
        {
          const float4 w0 = *(const float4*)(Wk + (size_t)r0*TU + cbg);
          const float4 w1 = *(const float4*)(Wk + (size_t)r1*TU + cbg);
          #pragma unroll
          for (int b=0;b<8;++b){
            fma4(aX[b], w0, hlf[b*1024 + 896 + ks*2]);
            fma4(aX[b], w1, hlf[b*1024 + 897 + ks*2]);
          }
        }
        if (g < 2){
          #pragma unroll
          for (int b=0;b<8;++b){
            aW[b].x += aX[b].x; aW[b].y += aX[b].y;
            aW[b].z += aX[b].z; aW[b].w += aX[b].w;
          }
          bf8(aW);
          if (lane < 8){
            float* dst = wredf + wv*288 + lane*36;
            #pragma unroll
            for (int b=0;b<8;++b) *(float4*)(dst + b*4) = aW[b];
          }
          __syncthreads();
          if (tid < 256){
            const int b = tid>>5, ci = tid&31;
            float s = 0.f;
            #pragma unroll
            for (int w=0; w<8; ++w) s += wredf[w*288 + (ci>>2)*36 + b*4 + (ci&3)];
            const int col = g*896 + U0 + ci;
            const float val = s + bias[col] + bias[TU + col];
            gstf(pre + b*TU + col, val);
            gbuf[(b*32 + ci)*4 + g] = val;
          }
          __syncthreads();
        } else {
          bf8(aW);
          if (lane < 8){
            float* dst = wredf + wv*288 + lane*36;
            #pragma unroll
            for (int b=0;b<8;++b) *(float4*)(dst + b*4) = aW[b];
          }
          __syncthreads();
          if (tid < 256){
            const int b = tid>>5, ci = tid&31;
            float s = 0.f;
            #pragma unroll
            for (int w=0; w<8; ++w) s += wredf[w*288 + (ci>>2)*36 + b*4 + (ci&3)];
            const int u = U0 + ci;
            const float val = s + bias[TU + 1792 + u];
            gstf(ihb + b*896 + u, val);
            gbuf[(b*32 + ci)*4 + 3] = val;
          }
          __syncthreads();
          bf8(aX);
          if (lane < 8){
            float* dst = wredf + wv*288 + lane*36;
            #pragma unroll
            for (int b=0;b<8;++b) *(float4*)(dst + b*4) = aX[b];
          }
          __syncthreads();
          if (tid < 256){
            const int b = tid>>5, ci = tid&31;
            float s = 0.f;
            #pragma unroll
            for (int w=0; w<8; ++w) s += wredf[w*288 + (ci>>2)*36 + b*4 + (ci&3)];
            const int u = U0 + ci;
            const float val = s + bias[1792 + u];
            gstf(pre + b*TU + 1792 + u, val);
            gbuf[(b*32 + ci)*4 + 2] = val;
          }
          __syncthreads();
        }
      }

      if (bk < 14){
        // coarse gates epilogue: needs fv(t-1)
        wait_slots(SFV, 8, (uint32_t)t, tid);
        if (tid < 256){
          const int b = tid>>5, ub = tid&31, u = U0 + ub;
          const float fv = gldf(fvsB + ((t+1)&1)*8 + b);
          const float* gb = gbuf + (b*32 + ub)*4;
          const float az = gb[0] + fv*Wk[(size_t)81*TU + u];
          const float ar = gb[1] + fv*Wk[(size_t)81*TU + 896 + u];
          const float ax = gb[2] + fv*Wk[(size_t)81*TU + 1792 + u];
          const float z = sig_f(az), r = sig_f(ar);
          const float hh = tanh_f(ax + r*gb[3]);
          gstf(h0c + b*HU + u, z*hlf[b*1024 + u] + (1.0f - z)*hh);
        }
      }
      publish_slot(SG + bk*32, (uint32_t)(t+1), tid);
    }
  } else if (bk < 56){
    // ================= head block j: (C) y1c slice + partial lgtC; (F) y1f slice + partial lgtF =================
    const int j = bk - 28;
    float* hstg = (float*)smem;                 // 3584 floats
    float* red1 = (float*)(smem + 14336);       // 512 floats
    float* y1s  = (float*)(smem + 16384);       // 128 floats
    const int outp = tid & 127, ks4 = tid >> 7; // out = (b,c), 4-way ksplit
    const int ob = outp >> 4, oc = outp & 15;
    const int i0 = ks4*112;

    for (int t=0; t<TT; ++t){
      // ---------- phase C ----------
      wait_slots(SG, 14, (uint32_t)(t+1), tid);
      for (int i=tid;i<3584;i+=NTH) hstg[i] = gldf(h0c + i);
      __syncthreads();
      {
        float s = 0.f;
        const float* hb = hstg + ob*HU;
        const float* wb = W1c + (size_t)i0*HU + j*16 + oc;
        #pragma unroll 4
        for (int i=0;i<112;++i) s += hb[i0+i]*wb[(size_t)i*HU];
        red1[outp*4 + ks4] = s;
      }
      __syncthreads();
      if (tid < 128){
        const float v = (red1[tid*4+0]+red1[tid*4+1])+(red1[tid*4+2]+red1[tid*4+3]);
        y1s[tid] = fmaxf(v + b1c[j*16 + (tid&15)], 0.0f);
      }
      __syncthreads();
      #pragma unroll
      for (int p=0;p<4;++p){
        const int o2 = p*512 + tid;
        const int b = o2 >> 8, cc = o2 & 255;
        float s2 = 0.f;
        #pragma unroll
        for (int i=0;i<16;++i) s2 += y1s[b*16+i]*W2c[(size_t)(j*16+i)*CC + cc];
        gstf(plgtC + j*2048 + o2, s2);
      }
      publish_slot(SYC + j*32, (uint32_t)(t+1), tid);

      // ---------- phase F ----------
      wait_slots(SH1HI, 8, (uint32_t)(t+1), tid);
      const int hsN = ((t+1)&1)*7168;
      for (int i=tid;i<3584;i+=NTH){
        const int b = i/HU, ii = i - b*HU;
        hstg[i] = gldf(hgl + hsN + b*U + HU + ii);
      }
      __syncthreads();
      {
        float s = 0.f;
        const float* hb = hstg + ob*HU;
        const float* wb = W1f + (size_t)i0*HU + j*16 + oc;
        #pragma unroll 4
        for (int i=0;i<112;++i) s += hb[i0+i]*wb[(size_t)i*HU];
        red1[outp*4 + ks4] = s;
      }
      __syncthreads();
      if (tid < 128){
        const float v = (red1[tid*4+0]+red1[tid*4+1])+(red1[tid*4+2]+red1[tid*4+3]);
        y1s[tid] = fmaxf(v + b1f[j*16 + (tid&15)], 0.0f);
      }
      __syncthreads();
      #pragma unroll
      for (int p=0;p<4;++p){
        const int o2 = p*512 + tid;
        const int b = o2 >> 8, cc = o2 & 255;
        float s2 = 0.f;
        #pragma unroll
        for (int i=0;i<16;++i) s2 += y1s[b*16+i]*W2f[(size_t)(j*16+i)*CC + cc];
        gstf(plgtF + j*2048 + o2, s2);
      }
      publish_slot(SYF + j*32, (uint32_t)(t+1), tid);
    }
  } else if (bk < 64){
    // ================= sample_c + fine gates (b = bk-56) =================
    const int b = bk - 56;
    float* sredf = (float*)smem;
    int*   sredi = (int*)(smem + 64);
    for (int t=0; t<TT; ++t){
      const float gmb = (tid<256) ? gumbel_from(kc[2*t], kc[2*t+1], (uint32_t)(b*CC + tid)) : 0.f;
      wait_slots(SYC, 28, (uint32_t)(t+1), tid);
      wait_slots(SG, 28, (uint32_t)(t+1), tid);
      float logit = -3.402823466e38f;
      if (tid < 256){
        float s = 0.f;
        #pragma unroll
        for (int j=0;j<28;++j) s += gldf(plgtC + j*2048 + b*CC + tid);
        logit = s + b2c[tid];
      }
      float m = logit;
      #pragma unroll
      for (int d=1; d<64; d<<=1) m = fmaxf(m, __shfl_xor(m, d));
      if ((tid&63)==0) sredf[tid>>6] = m;
      __syncthreads();
      const float mx = fmaxf(fmaxf(sredf[0],sredf[1]), fmaxf(sredf[2],sredf[3]));
      __syncthreads();
      const float e = (tid<256) ? (float)exp((double)(logit - mx)) : 0.f;
      float ss = e;
      #pragma unroll
      for (int d=1; d<64; d<<=1) ss += __shfl_xor(ss, d);
      if ((tid&63)==0) sredf[tid>>6] = ss;
      __syncthreads();
      const float sum = (sredf[0]+sredf[1])+(sredf[2]+sredf[3]);
      __syncthreads();
      float v = (tid<256) ? (e/sum + gmb) : -3.402823466e38f;
      int bi = (tid<256) ? tid : (1<<30);
      #pragma unroll
      for (int d=1; d<64; d<<=1){
        const float ov = __shfl_xor(v, d);
        const int   oi = __shfl_xor(bi, d);
        if (ov > v || (ov == v && oi < bi)){ v = ov; bi = oi; }
      }
      if ((tid&63)==0){ sredf[tid>>6] = v; sredi[tid>>6] = bi; }
      __syncthreads();
      float bv = sredf[0]; int nc = sredi[0];
      #pragma unroll
      for (int w=1; w<4; ++w){
        if (sredf[w] > bv || (sredf[w] == bv && sredi[w] < nc)){ bv = sredf[w]; nc = sredi[w]; }
      }
      if (tid==0){
        gsti(nci + b, nc);
        gstf(ncvB + (t&1)*8 + b, (float)nc/255.0f*2.0f - 1.0f);
      }
      const float ncv = (float)nc/255.0f*2.0f - 1.0f;
      const float fv = gldf(fvsB + ((t+1)&1)*8 + b);
      const int hsO = (t&1)*7168, hsN = ((t+1)&1)*7168;
      if (tid < 448){
        const int u = 448 + tid;
        const float az = gldf(pre + b*TU + u)        + fv*Wk[(size_t)81*TU + u]        + ncv*Wk[(size_t)82*TU + u];
        const float ar = gldf(pre + b*TU + 896 + u)  + fv*Wk[(size_t)81*TU + 896 + u]  + ncv*Wk[(size_t)82*TU + 896 + u];
        const float ax = gldf(pre + b*TU + 1792 + u) + fv*Wk[(size_t)81*TU + 1792 + u] + ncv*Wk[(size_t)82*TU + 1792 + u];
        const float ih = gldf(ihb + b*896 + u);
        const float z = sig_f(az), r = sig_f(ar);
        const float hh = tanh_f(ax + r*ih);
        gstf(hgl + hsN + b*896 + u, z*gldf(hgl + hsO + b*896 + u) + (1.0f - z)*hh);
      }
      publish_slot(SH1HI + b*32, (uint32_t)(t+1), tid);
      if (tid < 448){
        const int u = tid;
        const float az = gldf(pre + b*TU + u)        + fv*Wk[(size_t)81*TU + u]        + ncv*Wk[(size_t)82*TU + u];
        const float ar = gldf(pre + b*TU + 896 + u)  + fv*Wk[(size_t)81*TU + 896 + u]  + ncv*Wk[(size_t)82*TU + 896 + u];
        const float ax = gldf(pre + b*TU + 1792 + u) + fv*Wk[(size_t)81*TU + 1792 + u] + ncv*Wk[(size_t)82*TU + 1792 + u];
        const float ih = gldf(ihb + b*896 + u);
        const float z = sig_f(az), r = sig_f(ar);
        const float hh = tanh_f(ax + r*ih);
        gstf(hgl + hsN + b*896 + u, z*gldf(hgl + hsO + b*896 + u) + (1.0f - z)*hh);
      }
      publish_slot(SH1 + b*32, (uint32_t)(t+1), tid);
    }
  } else {
    // ================= sample_f (b = bk-64) =================
    const int b = bk - 64;
    float* sredf = (float*)smem;
    int*   sredi = (int*)(smem + 64);
    for (int t=0; t<TT; ++t){
      const float gmb = (tid<256) ? gumbel_from(kf[2*t], kf[2*t+1], (uint32_t)(b*CC + tid)) : 0.f;
      wait_slots(SYF, 28, (uint32_t)(t+1), tid);
      float logit = -3.402823466e38f;
      if (tid < 256){
        float s = 0.f;
        #pragma unroll
        for (int j=0;j<28;++j) s += gldf(plgtF + j*2048 + b*CC + tid);
        logit = s + b2f[tid];
      }
      float m = logit;
      #pragma unroll
      for (int d=1; d<64; d<<=1) m = fmaxf(m, __shfl_xor(m, d));
      if ((tid&63)==0) sredf[tid>>6] = m;
      __syncthreads();
      const float mx = fmaxf(fmaxf(sredf[0],sredf[1]), fmaxf(sredf[2],sredf[3]));
      __syncthreads();
      const float e = (tid<256) ? (float)exp((double)(logit - mx)) : 0.f;
      float ss = e;
      #pragma unroll
      for (int d=1; d<64; d<<=1) ss += __shfl_xor(ss, d);
      if ((tid&63)==0) sredf[tid>>6] = ss;
      __syncthreads();
      const float sum = (sredf[0]+sredf[1])+(sredf[2]+sredf[3]);
      __syncthreads();
      float v = (tid<256) ? (e/sum + gmb) : -3.402823466e38f;
      int bi = (tid<256) ? tid : (1<<30);
      #pragma unroll
      for (int d=1; d<64; d<<=1){
        const float ov = __shfl_xor(v, d);
        const int   oi = __shfl_xor(bi, d);
        if (ov > v || (ov == v && oi < bi)){ v = ov; bi = oi; }
      }
      if ((tid&63)==0){ sredf[tid>>6] = v; sredi[tid>>6] = bi; }
      __syncthreads();
      float bv = sredf[0]; int nf = sredi[0];
      #pragma unroll
      for (int w=1; w<4; ++w){
        if (sredf[w] > bv || (sredf[w] == bv && sredi[w] < nf)){ bv = sredf[w]; nf = sredi[w]; }
      }
      if (tid==0){
        gstf(fvsB + (t&1)*8 + b, (float)nf/255.0f*2.0f - 1.0f);
        const int nc = gldi(nci + b);
        out[(size_t)b*TT + t] = ((float)nc*256.0f + (float)nf)/32767.5f - 1.0f;
      }
      publish_slot(SFV + b*32, (uint32_t)(t+1), tid);
    }
  }
}

extern "C" void kernel_launch(void* const* d_in, const int* in_sizes, int n_in,
                              void* d_out, int out_size, void* d_ws, size_t ws_size,
                              hipStream_t stream) {
  const float* mels = (const float*)d_in[0];
  const float* Wk   = (const float*)d_in[1];
  const float* Wr   = (const float*)d_in[2];
  const float* bias = (const float*)d_in[3];
  const float* W1c  = (const float*)d_in[4];
  const float* b1c  = (const float*)d_in[5];
  const float* W2c  = (const float*)d_in[6];
  const float* b2c  = (const float*)d_in[7];
  const float* W1f  = (const float*)d_in[8];
  const float* b1f  = (const float*)d_in[9];
  const float* W2f  = (const float*)d_in[10];
  const float* b2f  = (const float*)d_in[11];
  float* out = (float*)d_out;
  char* wsb = (char*)d_ws;

  uint32_t* kc = (uint32_t*)(wsb + O_KC);
  uint32_t* kf = (uint32_t*)(wsb + O_KF);

  hipMemsetAsync(d_ws, 0, WS_ZERO, stream);
  k_keys<<<2,256,0,stream>>>(kc, kf);

  void* args[] = { (void*)&mels, (void*)&Wk, (void*)&Wr, (void*)&bias,
                   (void*)&W1c, (void*)&b1c, (void*)&W2c, (void*)&b2c,
                   (void*)&W1f, (void*)&b1f, (void*)&W2f, (void*)&b2f,
                   (void*)&out, (void*)&wsb };
  hipLaunchCooperativeKernel((const void*)wavernn_persist, dim3(NBLK), dim3(NTH),
                             args, 0, stream);
}